// Round 3
// baseline (166.738 us; speedup 1.0000x reference)
//
#include <hip/hip_runtime.h>
#include <hip/hip_bf16.h>

typedef __attribute__((ext_vector_type(8))) short bf16x8;
typedef __attribute__((ext_vector_type(4))) short s16x4;
typedef __attribute__((ext_vector_type(4))) float f32x4;

__device__ __forceinline__ short f2bf(float f) {
    __hip_bfloat16 h = __float2bfloat16(f);
    short s;
    __builtin_memcpy(&s, &h, 2);
    return s;
}

__device__ __forceinline__ float lrelu(float v) {
    return fmaxf(v, 0.05f * v);   // slope in (0,1)
}

#define MFMA(a, b, c) __builtin_amdgcn_mfma_f32_16x16x32_bf16((a), (b), (c), 0, 0, 0)

// ---------------------------------------------------------------------------
// Pre-kernel: z (fp32, 100000x128) -> zb (bf16, 100001 rows, fragment order).
// Row 0 = zeros (pad). Row r>=1 = z[r-1]. Per row: 16 chunks of 8 bf16;
// chunk (s,g) holds elems {32s+4g+0..3, 32s+16+4g+0..3} == the bf16x8 the
// gather lane (g,*) needs at k-step s. Writes are perfectly coalesced.
// ---------------------------------------------------------------------------
__global__ __launch_bounds__(256) void convert_z_kernel(
    const float* __restrict__ z, short* __restrict__ zb, int rows_p1)
{
    const int c = blockIdx.x * 256 + threadIdx.x;
    if (c >= rows_p1 * 16) return;
    const int row = c >> 4;
    const int s = (c >> 2) & 3;
    const int g = c & 3;
    bf16x8 v = {0, 0, 0, 0, 0, 0, 0, 0};
    if (row > 0) {
        const float* src = z + (size_t)(row - 1) * 128 + 32 * s + 4 * g;
        float4 a = *reinterpret_cast<const float4*>(src);
        float4 b = *reinterpret_cast<const float4*>(src + 16);
        v[0] = f2bf(a.x); v[1] = f2bf(a.y); v[2] = f2bf(a.z); v[3] = f2bf(a.w);
        v[4] = f2bf(b.x); v[5] = f2bf(b.y); v[6] = f2bf(b.z); v[7] = f2bf(b.w);
    }
    *reinterpret_cast<bf16x8*>(zb + (size_t)c * 8) = v;
}

// ---------------------------------------------------------------------------
// Main kernel (bf16 table). Per wave: one n. h1^T = W1*X^T, h2^T = W2*lrelu,
// max over 32 positions, write 128 features. k-slot convention both GEMMs:
// group g holds k_local {4g+i|i<4} u {16+4g+(i-4)|i>=4} = C/D row ownership,
// so GEMM1's D feeds GEMM2's B in-register. Weights in LDS fragment order.
// Gather is double-buffered: issue n+1's loads before computing n.
// ---------------------------------------------------------------------------
struct WaveCtx {
    const bf16x8* wv;   // LDS weights
    const int* neigh;
    float* out;
    int lane, g, u, n_rows;
};

__device__ __forceinline__ void gather_bx(const short* __restrict__ zb,
                                          unsigned ia, unsigned ib, int g,
                                          bf16x8 (&bx)[2][4])
{
    const bf16x8* p0 = reinterpret_cast<const bf16x8*>(zb + (size_t)ia * 128) + g;
    const bf16x8* p1 = reinterpret_cast<const bf16x8*>(zb + (size_t)ib * 128) + g;
    #pragma unroll
    for (int s = 0; s < 4; ++s) {
        bx[0][s] = p0[s * 4];
        bx[1][s] = p1[s * 4];
    }
}

__device__ __forceinline__ void compute_n(const WaveCtx& cx, bf16x8 (&bx)[2][4], int n)
{
    f32x4 d2[4][2];
    #pragma unroll
    for (int b2 = 0; b2 < 4; ++b2) {
        d2[b2][0] = (f32x4){0.f, 0.f, 0.f, 0.f};
        d2[b2][1] = (f32x4){0.f, 0.f, 0.f, 0.f};
    }
    float V1[16], V2[16];

    #pragma unroll
    for (int s2 = 0; s2 < 2; ++s2) {
        bf16x8 p2[2];
        #pragma unroll
        for (int h = 0; h < 2; ++h) {
            const int b = 2 * s2 + h;
            f32x4 d1[2];
            d1[0] = (f32x4){0.f, 0.f, 0.f, 0.f};
            d1[1] = (f32x4){0.f, 0.f, 0.f, 0.f};
            #pragma unroll
            for (int s = 0; s < 4; ++s) {
                const bf16x8 wf = cx.wv[((b << 2) + s) * 64 + cx.lane];
                d1[0] = MFMA(wf, bx[0][s], d1[0]);
                d1[1] = MFMA(wf, bx[1][s], d1[1]);
            }
            #pragma unroll
            for (int t = 0; t < 2; ++t) {
                #pragma unroll
                for (int q = 0; q < 4; ++q) {
                    float v = lrelu(d1[t][q]);
                    d1[t][q] = v;
                    p2[t][4 * h + q] = f2bf(v);
                }
            }
            #pragma unroll
            for (int q = 0; q < 4; ++q)
                V1[b * 4 + q] = fmaxf(d1[0][q], d1[1][q]);
        }
        #pragma unroll
        for (int b2 = 0; b2 < 4; ++b2) {
            const bf16x8 wf = cx.wv[1024 + ((b2 << 1) + s2) * 64 + cx.lane];
            d2[b2][0] = MFMA(wf, p2[0], d2[b2][0]);
            d2[b2][1] = MFMA(wf, p2[1], d2[b2][1]);
        }
    }

    #pragma unroll
    for (int b2 = 0; b2 < 4; ++b2) {
        #pragma unroll
        for (int q = 0; q < 4; ++q)
            V2[b2 * 4 + q] = lrelu(fmaxf(d2[b2][0][q], d2[b2][1][q]));
    }

    // halving-fold max over the 16 lanes of each k-group; lane u ends with V[u]
    const int u = cx.u;
    #pragma unroll
    for (int k = 0; k < 4; ++k) {
        const int m = 1 << k;
        const bool hi = (u & m) != 0;
        #pragma unroll
        for (int j = 0; j < (8 >> k); ++j) {
            float k1 = hi ? V1[2 * j + 1] : V1[2 * j];
            float s1 = hi ? V1[2 * j] : V1[2 * j + 1];
            float k2 = hi ? V2[2 * j + 1] : V2[2 * j];
            float s2v = hi ? V2[2 * j] : V2[2 * j + 1];
            V1[j] = fmaxf(k1, __shfl_xor(s1, m, 64));
            V2[j] = fmaxf(k2, __shfl_xor(s2v, m, 64));
        }
    }

    // lane (g,u) holds feature o = 16*(u>>2)+4g+(u&3); permute so lane l holds
    // feature l, then two contiguous 256B stores.
    const int l = cx.lane;
    const int src = 16 * ((l >> 2) & 3) + ((l >> 4) << 2) + (l & 3);
    float v1 = __shfl(V1[0], src, 64);
    float v2 = __shfl(V2[0], src, 64);
    float* op = cx.out + (size_t)n * 128;
    op[l] = v1;
    op[64 + l] = v2;
}

__global__ __launch_bounds__(256, 3) void neigh_enco_bf16_kernel(
    const short* __restrict__ zb,
    const int* __restrict__ neigh,
    const float* __restrict__ w1,
    const float* __restrict__ w2,
    float* __restrict__ out,
    int n_rows)
{
    __shared__ __align__(16) short wlds[12288];   // 16 w1 frags + 8 w2 frags

    const int tid = threadIdx.x;
    const int lane = tid & 63;
    const int g = lane >> 4;
    const int u = lane & 15;

    // one-time: w1,w2 fp32 -> bf16 fragments in LDS
    #pragma unroll
    for (int j = 0; j < 12; ++j) {
        const int c = tid + (j << 8);
        const float* src;
        int row, col, fbase;
        if (c < 2048) {            // w1: 64x128
            row = c >> 5; col = (c & 31) << 2;
            src = w1 + row * 128 + col;
            fbase = ((row >> 4) << 2) + (col >> 5);
        } else {                   // w2: 64x64
            const int c2 = c - 2048;
            row = c2 >> 4; col = (c2 & 15) << 2;
            src = w2 + row * 64 + col;
            fbase = 16 + ((row >> 4) << 1) + (col >> 5);
        }
        const int rem = col & 31;
        const int gg = (rem >> 2) & 3;
        const int eh = rem >> 4;
        float4 v = *reinterpret_cast<const float4*>(src);
        s16x4 p;
        p[0] = f2bf(v.x); p[1] = f2bf(v.y); p[2] = f2bf(v.z); p[3] = f2bf(v.w);
        const int idx = ((fbase << 6) + (gg << 4) + (row & 15)) * 8 + (eh << 2);
        *reinterpret_cast<s16x4*>(&wlds[idx]) = p;
    }
    __syncthreads();

    WaveCtx cx;
    cx.wv = reinterpret_cast<const bf16x8*>(wlds);
    cx.neigh = neigh;
    cx.out = out;
    cx.lane = lane; cx.g = g; cx.u = u; cx.n_rows = n_rows;

    const int waves_per_blk = blockDim.x >> 6;
    const int nwaves = gridDim.x * waves_per_blk;
    int n = blockIdx.x * waves_per_blk + (tid >> 6);
    if (n >= n_rows) return;

    bf16x8 bxA[2][4], bxB[2][4];

    // prologue: gather(n) -> A; idx(n+nw) staged
    unsigned ia = (unsigned)neigh[n * 32 + u];
    unsigned ib = (unsigned)neigh[n * 32 + 16 + u];
    gather_bx(zb, ia, ib, g, bxA);
    int n1 = n + nwaves;
    unsigned ja = 0, jb = 0;
    if (n1 < n_rows) { ja = (unsigned)neigh[n1 * 32 + u]; jb = (unsigned)neigh[n1 * 32 + 16 + u]; }

    while (true) {
        // issue gather(n+nw) -> B; prefetch idx(n+2nw)
        gather_bx(zb, ja, jb, g, bxB);
        {
            const int n2 = n + 2 * nwaves;
            ia = 0; ib = 0;
            if (n2 < n_rows) { ia = (unsigned)neigh[n2 * 32 + u]; ib = (unsigned)neigh[n2 * 32 + 16 + u]; }
        }
        compute_n(cx, bxA, n);
        n += nwaves;
        if (n >= n_rows) break;

        // issue gather(n+nw) -> A; prefetch idx(n+2nw)
        gather_bx(zb, ia, ib, g, bxA);
        {
            const int n2 = n + 2 * nwaves;
            ja = 0; jb = 0;
            if (n2 < n_rows) { ja = (unsigned)neigh[n2 * 32 + u]; jb = (unsigned)neigh[n2 * 32 + 16 + u]; }
        }
        compute_n(cx, bxB, n);
        n += nwaves;
        if (n >= n_rows) break;
    }
}

// ---------------------------------------------------------------------------
// Fallback (ws too small): proven R2 fp32-gather kernel, unchanged semantics.
// ---------------------------------------------------------------------------
__global__ __launch_bounds__(256, 3) void neigh_enco_fp32_kernel(
    const float* __restrict__ z,
    const int* __restrict__ neigh,
    const float* __restrict__ w1,
    const float* __restrict__ w2,
    float* __restrict__ out,
    int n_rows, int z_rows)
{
    __shared__ __align__(16) short wlds[12288];
    const int tid = threadIdx.x;
    const int lane = tid & 63;
    const int g = lane >> 4;
    const int u = lane & 15;

    #pragma unroll
    for (int j = 0; j < 12; ++j) {
        const int c = tid + (j << 8);
        const float* src;
        int row, col, fbase;
        if (c < 2048) {
            row = c >> 5; col = (c & 31) << 2;
            src = w1 + row * 128 + col;
            fbase = ((row >> 4) << 2) + (col >> 5);
        } else {
            const int c2 = c - 2048;
            row = c2 >> 4; col = (c2 & 15) << 2;
            src = w2 + row * 64 + col;
            fbase = 16 + ((row >> 4) << 1) + (col >> 5);
        }
        const int rem = col & 31;
        const int gg = (rem >> 2) & 3;
        const int eh = rem >> 4;
        float4 v = *reinterpret_cast<const float4*>(src);
        s16x4 p;
        p[0] = f2bf(v.x); p[1] = f2bf(v.y); p[2] = f2bf(v.z); p[3] = f2bf(v.w);
        const int idx = ((fbase << 6) + (gg << 4) + (row & 15)) * 8 + (eh << 2);
        *reinterpret_cast<s16x4*>(&wlds[idx]) = p;
    }
    __syncthreads();

    WaveCtx cx;
    cx.wv = reinterpret_cast<const bf16x8*>(wlds);
    cx.neigh = neigh; cx.out = out;
    cx.lane = lane; cx.g = g; cx.u = u; cx.n_rows = n_rows;

    const int waves_per_blk = blockDim.x >> 6;
    const int wave = blockIdx.x * waves_per_blk + (tid >> 6);
    const int nwaves = gridDim.x * waves_per_blk;
    const unsigned zu = (unsigned)z_rows;

    for (int n = wave; n < n_rows; n += nwaves) {
        unsigned r0 = (unsigned)neigh[n * 32 + u] - 1u;
        unsigned r1 = (unsigned)neigh[n * 32 + 16 + u] - 1u;
        bf16x8 bx[2][4];
        #pragma unroll
        for (int t = 0; t < 2; ++t) {
            const unsigned r = t ? r1 : r0;
            const bool valid = r < zu;
            const float* base = z + (size_t)r * 128 + 4 * g;
            #pragma unroll
            for (int s = 0; s < 4; ++s) {
                float4 lo = make_float4(0.f, 0.f, 0.f, 0.f);
                float4 hi = make_float4(0.f, 0.f, 0.f, 0.f);
                if (valid) {
                    lo = *reinterpret_cast<const float4*>(base + 32 * s);
                    hi = *reinterpret_cast<const float4*>(base + 32 * s + 16);
                }
                bf16x8 f;
                f[0] = f2bf(lo.x); f[1] = f2bf(lo.y); f[2] = f2bf(lo.z); f[3] = f2bf(lo.w);
                f[4] = f2bf(hi.x); f[5] = f2bf(hi.y); f[6] = f2bf(hi.z); f[7] = f2bf(hi.w);
                bx[t][s] = f;
            }
        }
        compute_n(cx, bx, n);
    }
}

extern "C" void kernel_launch(void* const* d_in, const int* in_sizes, int n_in,
                              void* d_out, int out_size, void* d_ws, size_t ws_size,
                              hipStream_t stream) {
    const float* z     = (const float*)d_in[0];
    const int*   neigh = (const int*)d_in[1];
    const float* w1    = (const float*)d_in[2];
    const float* w2    = (const float*)d_in[3];
    float* out = (float*)d_out;
    const int z_rows = in_sizes[0] / 128;
    const int n_rows = in_sizes[1] / 32;
    const int rows_p1 = z_rows + 1;

    const size_t zb_bytes = (size_t)rows_p1 * 128 * sizeof(short);
    if (ws_size >= zb_bytes) {
        short* zb = (short*)d_ws;
        const int chunks = rows_p1 * 16;
        hipLaunchKernelGGL(convert_z_kernel, dim3((chunks + 255) / 256), dim3(256),
                           0, stream, z, zb, rows_p1);
        hipLaunchKernelGGL(neigh_enco_bf16_kernel, dim3(2048), dim3(256), 0, stream,
                           zb, neigh, w1, w2, out, n_rows);
    } else {
        hipLaunchKernelGGL(neigh_enco_fp32_kernel, dim3(2048), dim3(256), 0, stream,
                           z, neigh, w1, w2, out, n_rows, z_rows);
    }
}

// Round 4
// 90.624 us; speedup vs baseline: 1.8399x; 1.8399x over previous
//
#include <hip/hip_runtime.h>
#include <hip/hip_bf16.h>

typedef __attribute__((ext_vector_type(8))) short bf16x8;
typedef __attribute__((ext_vector_type(4))) short s16x4;
typedef __attribute__((ext_vector_type(4))) float f32x4;

__device__ __forceinline__ short f2bf(float f) {
    __hip_bfloat16 h = __float2bfloat16(f);
    short s;
    __builtin_memcpy(&s, &h, 2);
    return s;
}

__device__ __forceinline__ float lrelu(float v) {
    return fmaxf(v, 0.05f * v);   // slope in (0,1)
}

#define MFMA(a, b, c) __builtin_amdgcn_mfma_f32_16x16x32_bf16((a), (b), (c), 0, 0, 0)

// ---------------------------------------------------------------------------
// Kernel 1: per-row MLP. cat[row] = [lrelu(W1 z_row); lrelu(W2 lrelu(W1 z_row))]
// for table rows 0..rows_p1-1 (row 0 = zeros pad -> MLP gives exact zeros).
// Swapped-operand MFMA: D = W * X^T, 32 sequential rows per wave (2 col-tiles).
// k-slot convention (both GEMMs): group g=lane>>4 holds k_local
// {4g+i|i<4} u {16+4g+(i-4)|i>=4} == C/D row ownership (row=4g+reg), so
// GEMM1's D feeds GEMM2's B in-register. Weights in LDS fragment order.
// Output row layout: plain [row][feature], bf16 (256B/row) for the gather.
// ---------------------------------------------------------------------------
__global__ __launch_bounds__(256, 3) void mlp_rows_kernel(
    const float* __restrict__ z,
    const float* __restrict__ w1,
    const float* __restrict__ w2,
    short* __restrict__ cat,
    int rows_p1)
{
    __shared__ __align__(16) short wlds[12288];   // 16 w1 frags + 8 w2 frags

    const int tid = threadIdx.x;
    const int lane = tid & 63;
    const int g = lane >> 4;
    const int u = lane & 15;

    // one-time: w1,w2 fp32 -> bf16 fragments in LDS (frag f, lane l @ f*1024+l*16)
    #pragma unroll
    for (int j = 0; j < 12; ++j) {
        const int c = tid + (j << 8);
        const float* src;
        int row, col, fbase;
        if (c < 2048) {            // w1: 64x128
            row = c >> 5; col = (c & 31) << 2;
            src = w1 + row * 128 + col;
            fbase = ((row >> 4) << 2) + (col >> 5);
        } else {                   // w2: 64x64
            const int c2 = c - 2048;
            row = c2 >> 4; col = (c2 & 15) << 2;
            src = w2 + row * 64 + col;
            fbase = 16 + ((row >> 4) << 1) + (col >> 5);
        }
        const int rem = col & 31;
        const int gg = (rem >> 2) & 3;
        const int eh = rem >> 4;
        float4 v = *reinterpret_cast<const float4*>(src);
        s16x4 p;
        p[0] = f2bf(v.x); p[1] = f2bf(v.y); p[2] = f2bf(v.z); p[3] = f2bf(v.w);
        const int idx = ((fbase << 6) + (gg << 4) + (row & 15)) * 8 + (eh << 2);
        *reinterpret_cast<s16x4*>(&wlds[idx]) = p;
    }
    __syncthreads();

    const bf16x8* __restrict__ wv = reinterpret_cast<const bf16x8*>(wlds);

    const int waves_per_blk = blockDim.x >> 6;
    const int wave = blockIdx.x * waves_per_blk + (tid >> 6);
    const int nwaves = gridDim.x * waves_per_blk;
    const int nchunks = (rows_p1 + 31) >> 5;

    for (int c = wave; c < nchunks; c += nwaves) {
        const int base = c << 5;
        const int r0 = base + u;         // tile-0 table row for this lane
        const int r1 = base + 16 + u;    // tile-1 table row

        bf16x8 bx[2][4];
        #pragma unroll
        for (int t = 0; t < 2; ++t) {
            const int r = t ? r1 : r0;
            const bool valid = (r >= 1) && (r < rows_p1);
            const float* srcp = z + (size_t)(r - 1) * 128 + 4 * g;
            #pragma unroll
            for (int s = 0; s < 4; ++s) {
                float4 lo = make_float4(0.f, 0.f, 0.f, 0.f);
                float4 hi = make_float4(0.f, 0.f, 0.f, 0.f);
                if (valid) {
                    lo = *reinterpret_cast<const float4*>(srcp + 32 * s);
                    hi = *reinterpret_cast<const float4*>(srcp + 32 * s + 16);
                }
                bf16x8 f;
                f[0] = f2bf(lo.x); f[1] = f2bf(lo.y); f[2] = f2bf(lo.z); f[3] = f2bf(lo.w);
                f[4] = f2bf(hi.x); f[5] = f2bf(hi.y); f[6] = f2bf(hi.z); f[7] = f2bf(hi.w);
                bx[t][s] = f;
            }
        }

        const bool st0 = r0 < rows_p1;
        const bool st1 = r1 < rows_p1;
        short* c0 = cat + (size_t)r0 * 128 + 4 * g;   // +16b+q within
        short* c1 = cat + (size_t)r1 * 128 + 4 * g;

        f32x4 d2[4][2];
        #pragma unroll
        for (int b2 = 0; b2 < 4; ++b2) {
            d2[b2][0] = (f32x4){0.f, 0.f, 0.f, 0.f};
            d2[b2][1] = (f32x4){0.f, 0.f, 0.f, 0.f};
        }

        #pragma unroll
        for (int s2 = 0; s2 < 2; ++s2) {
            bf16x8 p2[2];
            #pragma unroll
            for (int h = 0; h < 2; ++h) {
                const int b = 2 * s2 + h;
                f32x4 d1[2];
                d1[0] = (f32x4){0.f, 0.f, 0.f, 0.f};
                d1[1] = (f32x4){0.f, 0.f, 0.f, 0.f};
                #pragma unroll
                for (int s = 0; s < 4; ++s) {
                    const bf16x8 wf = wv[((b << 2) + s) * 64 + lane];
                    d1[0] = MFMA(wf, bx[0][s], d1[0]);
                    d1[1] = MFMA(wf, bx[1][s], d1[1]);
                }
                #pragma unroll
                for (int t = 0; t < 2; ++t) {
                    s16x4 pk;
                    #pragma unroll
                    for (int q = 0; q < 4; ++q) {
                        const short bv = f2bf(lrelu(d1[t][q]));
                        p2[t][4 * h + q] = bv;
                        pk[q] = bv;
                    }
                    // h1 features 16b+4g+q for row (base+16t+u)
                    if (t == 0 ? st0 : st1)
                        *reinterpret_cast<s16x4*>((t ? c1 : c0) + 16 * b) = pk;
                }
            }
            #pragma unroll
            for (int b2 = 0; b2 < 4; ++b2) {
                const bf16x8 wf = wv[1024 + ((b2 << 1) + s2) * 64 + lane];
                d2[b2][0] = MFMA(wf, p2[0], d2[b2][0]);
                d2[b2][1] = MFMA(wf, p2[1], d2[b2][1]);
            }
        }

        #pragma unroll
        for (int b2 = 0; b2 < 4; ++b2) {
            #pragma unroll
            for (int t = 0; t < 2; ++t) {
                s16x4 pk;
                #pragma unroll
                for (int q = 0; q < 4; ++q)
                    pk[q] = f2bf(lrelu(d2[b2][t][q]));
                if (t == 0 ? st0 : st1)
                    *reinterpret_cast<s16x4*>((t ? c1 : c0) + 64 + 16 * b2) = pk;
            }
        }
    }
}

// ---------------------------------------------------------------------------
// Kernel 2: gather + elementwise max. Per wave: one n. 32 row reads, each with
// a wave-uniform (readlane -> SGPR) base + lane*4B: one coalesced 256B request.
// All 32 loads issued before any use -> 32 outstanding VMEM ops per wave.
// Lane l owns features {2l, 2l+1}; bf16 pair unpacked to fp32 for the max.
// ---------------------------------------------------------------------------
__global__ __launch_bounds__(256) void gather_max_kernel(
    const unsigned int* __restrict__ cat,   // [rows][64] uint = 2 bf16 each
    const int* __restrict__ neigh,
    float* __restrict__ out,
    int n_rows)
{
    const int tid = threadIdx.x;
    const int lane = tid & 63;
    const int waves_per_blk = blockDim.x >> 6;
    const int wave0 = blockIdx.x * waves_per_blk + (tid >> 6);
    const int nwaves = gridDim.x * waves_per_blk;

    for (int n = wave0; n < n_rows; n += nwaves) {
        const int idxv = neigh[n * 32 + (lane & 31)];

        unsigned int d[32];
        #pragma unroll
        for (int p = 0; p < 32; ++p) {
            const unsigned rp = (unsigned)__builtin_amdgcn_readlane(idxv, p);
            d[p] = cat[(size_t)rp * 64 + lane];
        }

        float m0 = __uint_as_float(d[0] << 16);
        float m1 = __uint_as_float(d[0] & 0xffff0000u);
        #pragma unroll
        for (int p = 1; p < 32; ++p) {
            m0 = fmaxf(m0, __uint_as_float(d[p] << 16));
            m1 = fmaxf(m1, __uint_as_float(d[p] & 0xffff0000u));
        }

        *reinterpret_cast<float2*>(out + (size_t)n * 128 + 2 * lane) =
            make_float2(m0, m1);
    }
}

// ---------------------------------------------------------------------------
// Fallback (ws too small): proven fused fp32-gather kernel (R2 semantics).
// ---------------------------------------------------------------------------
struct WaveCtx {
    const bf16x8* wv;
    const int* neigh;
    float* out;
    int lane, g, u, n_rows;
};

__device__ __forceinline__ void compute_n(const WaveCtx& cx, bf16x8 (&bx)[2][4], int n)
{
    f32x4 d2[4][2];
    #pragma unroll
    for (int b2 = 0; b2 < 4; ++b2) {
        d2[b2][0] = (f32x4){0.f, 0.f, 0.f, 0.f};
        d2[b2][1] = (f32x4){0.f, 0.f, 0.f, 0.f};
    }
    float V1[16], V2[16];

    #pragma unroll
    for (int s2 = 0; s2 < 2; ++s2) {
        bf16x8 p2[2];
        #pragma unroll
        for (int h = 0; h < 2; ++h) {
            const int b = 2 * s2 + h;
            f32x4 d1[2];
            d1[0] = (f32x4){0.f, 0.f, 0.f, 0.f};
            d1[1] = (f32x4){0.f, 0.f, 0.f, 0.f};
            #pragma unroll
            for (int s = 0; s < 4; ++s) {
                const bf16x8 wf = cx.wv[((b << 2) + s) * 64 + cx.lane];
                d1[0] = MFMA(wf, bx[0][s], d1[0]);
                d1[1] = MFMA(wf, bx[1][s], d1[1]);
            }
            #pragma unroll
            for (int t = 0; t < 2; ++t) {
                #pragma unroll
                for (int q = 0; q < 4; ++q) {
                    float v = lrelu(d1[t][q]);
                    d1[t][q] = v;
                    p2[t][4 * h + q] = f2bf(v);
                }
            }
            #pragma unroll
            for (int q = 0; q < 4; ++q)
                V1[b * 4 + q] = fmaxf(d1[0][q], d1[1][q]);
        }
        #pragma unroll
        for (int b2 = 0; b2 < 4; ++b2) {
            const bf16x8 wf = cx.wv[1024 + ((b2 << 1) + s2) * 64 + cx.lane];
            d2[b2][0] = MFMA(wf, p2[0], d2[b2][0]);
            d2[b2][1] = MFMA(wf, p2[1], d2[b2][1]);
        }
    }

    #pragma unroll
    for (int b2 = 0; b2 < 4; ++b2) {
        #pragma unroll
        for (int q = 0; q < 4; ++q)
            V2[b2 * 4 + q] = lrelu(fmaxf(d2[b2][0][q], d2[b2][1][q]));
    }

    const int u = cx.u;
    #pragma unroll
    for (int k = 0; k < 4; ++k) {
        const int m = 1 << k;
        const bool hi = (u & m) != 0;
        #pragma unroll
        for (int j = 0; j < (8 >> k); ++j) {
            float k1 = hi ? V1[2 * j + 1] : V1[2 * j];
            float s1 = hi ? V1[2 * j] : V1[2 * j + 1];
            float k2 = hi ? V2[2 * j + 1] : V2[2 * j];
            float s2v = hi ? V2[2 * j] : V2[2 * j + 1];
            V1[j] = fmaxf(k1, __shfl_xor(s1, m, 64));
            V2[j] = fmaxf(k2, __shfl_xor(s2v, m, 64));
        }
    }

    const int l = cx.lane;
    const int src = 16 * ((l >> 2) & 3) + ((l >> 4) << 2) + (l & 3);
    float v1 = __shfl(V1[0], src, 64);
    float v2 = __shfl(V2[0], src, 64);
    float* op = cx.out + (size_t)n * 128;
    op[l] = v1;
    op[64 + l] = v2;
}

__global__ __launch_bounds__(256, 3) void neigh_enco_fp32_kernel(
    const float* __restrict__ z,
    const int* __restrict__ neigh,
    const float* __restrict__ w1,
    const float* __restrict__ w2,
    float* __restrict__ out,
    int n_rows, int z_rows)
{
    __shared__ __align__(16) short wlds[12288];
    const int tid = threadIdx.x;
    const int lane = tid & 63;
    const int g = lane >> 4;
    const int u = lane & 15;

    #pragma unroll
    for (int j = 0; j < 12; ++j) {
        const int c = tid + (j << 8);
        const float* src;
        int row, col, fbase;
        if (c < 2048) {
            row = c >> 5; col = (c & 31) << 2;
            src = w1 + row * 128 + col;
            fbase = ((row >> 4) << 2) + (col >> 5);
        } else {
            const int c2 = c - 2048;
            row = c2 >> 4; col = (c2 & 15) << 2;
            src = w2 + row * 64 + col;
            fbase = 16 + ((row >> 4) << 1) + (col >> 5);
        }
        const int rem = col & 31;
        const int gg = (rem >> 2) & 3;
        const int eh = rem >> 4;
        float4 v = *reinterpret_cast<const float4*>(src);
        s16x4 p;
        p[0] = f2bf(v.x); p[1] = f2bf(v.y); p[2] = f2bf(v.z); p[3] = f2bf(v.w);
        const int idx = ((fbase << 6) + (gg << 4) + (row & 15)) * 8 + (eh << 2);
        *reinterpret_cast<s16x4*>(&wlds[idx]) = p;
    }
    __syncthreads();

    WaveCtx cx;
    cx.wv = reinterpret_cast<const bf16x8*>(wlds);
    cx.neigh = neigh; cx.out = out;
    cx.lane = lane; cx.g = g; cx.u = u; cx.n_rows = n_rows;

    const int waves_per_blk = blockDim.x >> 6;
    const int wave = blockIdx.x * waves_per_blk + (tid >> 6);
    const int nwaves = gridDim.x * waves_per_blk;
    const unsigned zu = (unsigned)z_rows;

    for (int n = wave; n < n_rows; n += nwaves) {
        unsigned r0 = (unsigned)neigh[n * 32 + u] - 1u;
        unsigned r1 = (unsigned)neigh[n * 32 + 16 + u] - 1u;
        bf16x8 bx[2][4];
        #pragma unroll
        for (int t = 0; t < 2; ++t) {
            const unsigned r = t ? r1 : r0;
            const bool valid = r < zu;
            const float* base = z + (size_t)r * 128 + 4 * g;
            #pragma unroll
            for (int s = 0; s < 4; ++s) {
                float4 lo = make_float4(0.f, 0.f, 0.f, 0.f);
                float4 hi = make_float4(0.f, 0.f, 0.f, 0.f);
                if (valid) {
                    lo = *reinterpret_cast<const float4*>(base + 32 * s);
                    hi = *reinterpret_cast<const float4*>(base + 32 * s + 16);
                }
                bf16x8 f;
                f[0] = f2bf(lo.x); f[1] = f2bf(lo.y); f[2] = f2bf(lo.z); f[3] = f2bf(lo.w);
                f[4] = f2bf(hi.x); f[5] = f2bf(hi.y); f[6] = f2bf(hi.z); f[7] = f2bf(hi.w);
                bx[t][s] = f;
            }
        }
        compute_n(cx, bx, n);
    }
}

extern "C" void kernel_launch(void* const* d_in, const int* in_sizes, int n_in,
                              void* d_out, int out_size, void* d_ws, size_t ws_size,
                              hipStream_t stream) {
    const float* z     = (const float*)d_in[0];
    const int*   neigh = (const int*)d_in[1];
    const float* w1    = (const float*)d_in[2];
    const float* w2    = (const float*)d_in[3];
    float* out = (float*)d_out;
    const int z_rows = in_sizes[0] / 128;
    const int n_rows = in_sizes[1] / 32;
    const int rows_p1 = z_rows + 1;

    const size_t cat_bytes = (size_t)rows_p1 * 128 * sizeof(short);
    if (ws_size >= cat_bytes) {
        short* cat = (short*)d_ws;
        const int nchunks = (rows_p1 + 31) / 32;
        hipLaunchKernelGGL(mlp_rows_kernel, dim3((nchunks + 3) / 4), dim3(256),
                           0, stream, z, w1, w2, cat, rows_p1);
        hipLaunchKernelGGL(gather_max_kernel, dim3(2048), dim3(256), 0, stream,
                           (const unsigned int*)cat, neigh, out, n_rows);
    } else {
        hipLaunchKernelGGL(neigh_enco_fp32_kernel, dim3(2048), dim3(256), 0, stream,
                           z, neigh, w1, w2, out, n_rows, z_rows);
    }
}